// Round 10
// baseline (529.235 us; speedup 1.0000x reference)
//
#include <hip/hip_runtime.h>
#include <hip/hip_cooperative_groups.h>
#include <math.h>

// ---------------------------------------------------------------------------
// GCN forward. R9: dispatch count 12 -> 5. All graph-setup phases (zero+fuse,
// degree, scan, finalize+scale, CSR fill) fused into ONE cooperative kernel
// with grid.sync() phase barriers. k_time merged into k_heads grid. agg/gemm/
// heads keep dedicated launches (occupancy differs). Math identical to R8.
// ---------------------------------------------------------------------------

namespace cg = cooperative_groups;

typedef short short8 __attribute__((ext_vector_type(8)));
typedef float f32x4 __attribute__((ext_vector_type(4)));

static __device__ __forceinline__ unsigned short f2bf(float x) {  // RNE
  unsigned u = __float_as_uint(x);
  u += 0x7fff + ((u >> 16) & 1);
  return (unsigned short)(u >> 16);
}
static __device__ __forceinline__ unsigned pack2bf(float lo, float hi) {
  return ((unsigned)f2bf(hi) << 16) | (unsigned)f2bf(lo);
}
static __device__ __forceinline__ float bflo(unsigned u) {
  return __uint_as_float(u << 16);
}
static __device__ __forceinline__ float bfhi(unsigned u) {
  return __uint_as_float(u & 0xffff0000u);
}

// ---------------- setup params ---------------------------------------------
struct GP {
  const float* x0;
  const int* src;
  const int* dst;
  const float* W1;
  const float *Wt, *bt, *Wct, *bct;
  const float *Ws, *bs, *Wcs, *bcs;
  const float *Wa, *ba, *Wca, *bca;
  int* deg;
  int* row_off;
  int* bsum;
  int* cursor;
  float* dinv;
  unsigned short* csr;
  unsigned short* WfPk;
  unsigned short* W1Pk;
  float* bfb;
  unsigned* Yb;
  int N, E, gN;
};

// ---- phase 0: zero deg + fuse/pack weights (independent work) -------------
static __device__ __forceinline__ void ph_zero_fuse(const GP& p, int bid, int nb,
                                                    int tid) {
  for (int i = bid * 256 + tid; i < p.N; i += nb * 256) p.deg[i] = 0;
  for (int w = bid; w < 384; w += nb) {
    int i = tid;
    if (i < 128) {
      if (w >= 256) {  // pack W1 [128][128] -> [(k>>3)][col][k&7]
        int t = (w - 256) * 128 + i;
        int r = t >> 7, c = t & 127;
        p.W1Pk[((r >> 3) * 128 + c) * 8 + (r & 7)] = f2bf(p.W1[t]);
      } else {
        int c = w;
        float acc = 0.f, bacc = 0.f;
        if (c < 20) {
          for (int k = 0; k < 20; ++k) {
            float w2 = p.Wct[k * 20 + c];
            acc += p.Wt[i * 20 + k] * w2;
            bacc += p.bt[k] * w2;
          }
          bacc += p.bct[c];
        } else if (c < 50) {
          int cc = c - 20;
          for (int k = 0; k < 30; ++k) {
            float w2 = p.Wcs[k * 30 + cc];
            acc += p.Ws[i * 30 + k] * w2;
            bacc += p.bs[k] * w2;
          }
          bacc += p.bcs[cc];
        } else if (c < 250) {
          int cc = c - 50;
          for (int k = 0; k < 200; ++k) {
            float w2 = p.Wca[k * 200 + cc];
            acc += p.Wa[i * 200 + k] * w2;
            bacc += p.ba[k] * w2;
          }
          bacc += p.bca[cc];
        }
        p.WfPk[((i >> 3) * 256 + c) * 8 + (i & 7)] = f2bf(acc);
        if (i == 0) p.bfb[c] = bacc;
      }
    }
  }
}

// ---- phase 1: degree count ------------------------------------------------
static __device__ __forceinline__ void ph_deg(const GP& p, int bid, int nb,
                                              int tid) {
  for (int e = bid * 256 + tid; e < p.E; e += nb * 256)
    atomicAdd(&p.deg[p.dst[e]], 1);
}

// ---- phase 2: per-chunk exclusive scan ------------------------------------
static __device__ __forceinline__ void ph_scan_chunks(const GP& p, int bid,
                                                      int nb, int tid,
                                                      int* smi) {
  for (int c = bid; c < p.gN; c += nb) {
    int i = c * 256 + tid;
    int v = (i < p.N) ? p.deg[i] : 0;
    smi[tid] = v;
    __syncthreads();
#pragma unroll
    for (int o = 1; o < 256; o <<= 1) {
      int t = (tid >= o) ? smi[tid - o] : 0;
      __syncthreads();
      smi[tid] += t;
      __syncthreads();
    }
    if (i < p.N) p.row_off[i] = smi[tid] - v;
    if (tid == 255) p.bsum[c] = smi[255];
    __syncthreads();
  }
}

// ---- phase 3: scan chunk sums (single block) ------------------------------
static __device__ __forceinline__ void ph_scan_bsum(const GP& p, int tid,
                                                    int* smi) {
  int v = (tid < p.gN) ? p.bsum[tid] : 0;
  smi[tid] = v;
  __syncthreads();
#pragma unroll
  for (int o = 1; o < 256; o <<= 1) {
    int t = (tid >= o) ? smi[tid - o] : 0;
    __syncthreads();
    smi[tid] += t;
    __syncthreads();
  }
  if (tid < p.gN) p.bsum[tid] = smi[tid] - v;  // exclusive
}

// ---- phase 4: finalize row_off/cursor/dinv + prescale x0 -> bf16 ----------
static __device__ __forceinline__ void ph_finscale(const GP& p, int bid, int nb,
                                                   int tid) {
  int total = p.N * 64;
  for (int q = bid * 256 + tid; q < total; q += nb * 256) {
    int row = q >> 6;
    float d = rsqrtf((float)(p.deg[row] + 1));  // +1 self-loop
    if ((q & 63) == 0) {
      int ro = p.row_off[row] + p.bsum[row >> 8];
      p.row_off[row] = ro;
      p.cursor[row] = ro;
      p.dinv[row] = d;
    }
    float2 v = reinterpret_cast<const float2*>(p.x0)[q];
    p.Yb[q] = pack2bf(v.x * d, v.y * d);
  }
}

// ---- phase 5: CSR fill (uint16) -------------------------------------------
static __device__ __forceinline__ void ph_fill(const GP& p, int bid, int nb,
                                               int tid) {
  for (int e = bid * 256 + tid; e < p.E; e += nb * 256) {
    int d = p.dst[e];
    int pos = atomicAdd(&p.cursor[d], 1);
    p.csr[pos] = (unsigned short)p.src[e];
  }
}

// ---- cooperative setup kernel ---------------------------------------------
__global__ __launch_bounds__(256) void k_setup_coop(GP p) {
  cg::grid_group grid = cg::this_grid();
  __shared__ int smi[256];
  int bid = blockIdx.x, nb = gridDim.x, tid = threadIdx.x;
  ph_zero_fuse(p, bid, nb, tid);
  grid.sync();
  ph_deg(p, bid, nb, tid);
  grid.sync();
  ph_scan_chunks(p, bid, nb, tid, smi);
  grid.sync();
  if (bid == 0) ph_scan_bsum(p, tid, smi);
  grid.sync();
  ph_finscale(p, bid, nb, tid);
  grid.sync();
  ph_fill(p, bid, nb, tid);
}

// ---- aggregation on bf16 tables -------------------------------------------
__global__ __launch_bounds__(256) void k_agg(
    const unsigned* __restrict__ Y, unsigned* __restrict__ out,
    const int* __restrict__ row_off, const int* __restrict__ deg,
    const unsigned short* __restrict__ csr, const float* __restrict__ dinv,
    int n) {
  int wave = threadIdx.x >> 6;
  int lane = threadIdx.x & 63;
  int sub = lane >> 5;
  int sl = lane & 31;
  int i = blockIdx.x * 8 + wave * 2 + sub;
  if (i >= n) return;
  int start = row_off[i];
  int cnt = deg[i];
  const uint2* Yv = reinterpret_cast<const uint2*>(Y);
  float a0 = 0.f, a1 = 0.f, a2 = 0.f, a3 = 0.f;
  int j = 0;
  for (; j + 3 < cnt; j += 4) {
    int s0 = csr[start + j];
    int s1 = csr[start + j + 1];
    int s2 = csr[start + j + 2];
    int s3 = csr[start + j + 3];
    uint2 u0 = Yv[(size_t)s0 * 32 + sl];
    uint2 u1 = Yv[(size_t)s1 * 32 + sl];
    uint2 u2 = Yv[(size_t)s2 * 32 + sl];
    uint2 u3 = Yv[(size_t)s3 * 32 + sl];
    a0 += (bflo(u0.x) + bflo(u1.x)) + (bflo(u2.x) + bflo(u3.x));
    a1 += (bfhi(u0.x) + bfhi(u1.x)) + (bfhi(u2.x) + bfhi(u3.x));
    a2 += (bflo(u0.y) + bflo(u1.y)) + (bflo(u2.y) + bflo(u3.y));
    a3 += (bfhi(u0.y) + bfhi(u1.y)) + (bfhi(u2.y) + bfhi(u3.y));
  }
  for (; j < cnt; ++j) {
    int s0 = csr[start + j];
    uint2 u0 = Yv[(size_t)s0 * 32 + sl];
    a0 += bflo(u0.x);
    a1 += bfhi(u0.x);
    a2 += bflo(u0.y);
    a3 += bfhi(u0.y);
  }
  uint2 us = Yv[(size_t)i * 32 + sl];
  float di = dinv[i];
  uint2 r;
  r.x = pack2bf((a0 + bflo(us.x)) * di, (a1 + bfhi(us.x)) * di);
  r.y = pack2bf((a2 + bflo(us.y)) * di, (a3 + bfhi(us.y)) * di);
  reinterpret_cast<uint2*>(out)[(size_t)i * 32 + sl] = r;
}

// ---- stage 32 bf16 rows into LDS ------------------------------------------
static __device__ __forceinline__ void stage32(
    const short* __restrict__ A, short (*sAb)[136], int rowBase, int n, int tid) {
  for (int t = tid; t < 32 * 16; t += 256) {
    int r = t >> 4, c8 = t & 15;
    int gr = rowBase + r;
    short8 v = (short8){0, 0, 0, 0, 0, 0, 0, 0};
    if (gr < n) v = *reinterpret_cast<const short8*>(A + (size_t)gr * 128 + c8 * 8);
    *reinterpret_cast<short8*>(&sAb[r][c8 * 8]) = v;
  }
}

// ---- MFMA GEMM 128x128, col-split -----------------------------------------
__global__ __launch_bounds__(256) void k_mfma_gemm128(
    const short* __restrict__ A, const unsigned short* __restrict__ Wpk,
    const float* __restrict__ bias, const float* __restrict__ dinv,
    unsigned short* __restrict__ out, int n) {
  __shared__ short sAb[32][136];
  int rowBase = blockIdx.x * 32;
  stage32(A, sAb, rowBase, n, threadIdx.x);
  __syncthreads();
  int wave = threadIdx.x >> 6, lane = threadIdx.x & 63;
  int rg = wave >> 1, ch = wave & 1;
  int lr = lane & 15, lg = lane >> 4;
  int r0 = rowBase + rg * 16;
  short8 afr[4];
#pragma unroll
  for (int kk = 0; kk < 4; ++kk)
    afr[kk] = *reinterpret_cast<const short8*>(&sAb[rg * 16 + lr][kk * 32 + lg * 8]);
  f32x4 acc[4];
#pragma unroll
  for (int t = 0; t < 4; ++t) acc[t] = (f32x4){0.f, 0.f, 0.f, 0.f};
  const short8* Wp8 = reinterpret_cast<const short8*>(Wpk);
#pragma unroll
  for (int t = 0; t < 4; ++t) {
#pragma unroll
    for (int kk = 0; kk < 4; ++kk) {
      short8 bfr = Wp8[(kk * 4 + lg) * 128 + ch * 64 + t * 16 + lr];
      acc[t] = __builtin_amdgcn_mfma_f32_16x16x32_bf16(afr[kk], bfr, acc[t], 0, 0, 0);
    }
  }
  int rloc = r0 + lg * 4;
#pragma unroll
  for (int t = 0; t < 4; ++t) {
    int col = ch * 64 + t * 16 + lr;
    float b = bias[col];
#pragma unroll
    for (int reg = 0; reg < 4; ++reg) {
      int row = rloc + reg;
      if (row < n) {
        float v = fmaxf(acc[t][reg] + b, 0.f) * dinv[row];
        out[(size_t)row * 128 + col] = f2bf(v);
      }
    }
  }
}

// ---- heads (MFMA col-split + fused softmax) + time head, one grid ---------
__global__ __launch_bounds__(256) void k_heads_time(
    const short* __restrict__ A, const unsigned short* __restrict__ Wpk,
    const float* __restrict__ bfb, const float* __restrict__ x0,
    const float* __restrict__ Wtf, const float* __restrict__ btf,
    float* __restrict__ outT, float* __restrict__ outS,
    float* __restrict__ outTime, float* __restrict__ outA, int n) {
  int g32 = (n + 31) / 32;
  if ((int)blockIdx.x >= g32) {
    // ---------------- time head: softmax(x0 @ Wtf + btf), no LDS ----------
    int tb = blockIdx.x - g32;
    int j = threadIdx.x & 15;
    int rl = threadIdx.x >> 4;
    int r = tb * 16 + rl;
    if (r >= n) return;
    int jj = (j < 15) ? j : 14;
    float acc = btf[jj];
    const float4* xr = reinterpret_cast<const float4*>(x0 + (size_t)r * 128);
    for (int k4 = 0; k4 < 32; ++k4) {
      float4 xv = xr[k4];
      acc += xv.x * Wtf[(k4 * 4 + 0) * 15 + jj] + xv.y * Wtf[(k4 * 4 + 1) * 15 + jj] +
             xv.z * Wtf[(k4 * 4 + 2) * 15 + jj] + xv.w * Wtf[(k4 * 4 + 3) * 15 + jj];
    }
    float m = (j < 15) ? acc : -INFINITY;
#pragma unroll
    for (int o = 8; o; o >>= 1) m = fmaxf(m, __shfl_xor(m, o, 16));
    float e = (j < 15) ? __expf(acc - m) : 0.f;
    float s = e;
#pragma unroll
    for (int o = 8; o; o >>= 1) s += __shfl_xor(s, o, 16);
    if (j < 15) outTime[(size_t)r * 15 + j] = e / s;
    return;
  }
  // ---------------- heads ------------------------------------------------
  __shared__ short sAb[32][136];
  __shared__ float aM[2][2][16];
  __shared__ float aS[2][2][16];
  int rowBase = blockIdx.x * 32;
  stage32(A, sAb, rowBase, n, threadIdx.x);
  __syncthreads();
  int wave = threadIdx.x >> 6, lane = threadIdx.x & 63;
  int rg = wave >> 1, ch = wave & 1;
  int lr = lane & 15, lg = lane >> 4;
  int r0 = rowBase + rg * 16;
  int cb = ch * 128;
  short8 afr[4];
#pragma unroll
  for (int kk = 0; kk < 4; ++kk)
    afr[kk] = *reinterpret_cast<const short8*>(&sAb[rg * 16 + lr][kk * 32 + lg * 8]);
  f32x4 acc[8];
#pragma unroll
  for (int t = 0; t < 8; ++t) acc[t] = (f32x4){0.f, 0.f, 0.f, 0.f};
  const short8* Wp8 = reinterpret_cast<const short8*>(Wpk);
#pragma unroll
  for (int t = 0; t < 8; ++t) {
#pragma unroll
    for (int kk = 0; kk < 4; ++kk) {
      short8 bfr = Wp8[(kk * 4 + lg) * 256 + cb + t * 16 + lr];
      acc[t] = __builtin_amdgcn_mfma_f32_16x16x32_bf16(afr[kk], bfr, acc[t], 0, 0, 0);
    }
  }
  float bias_l[8];
#pragma unroll
  for (int t = 0; t < 8; ++t) bias_l[t] = bfb[cb + t * 16 + lr];
  float mTr[4], mSr[4], mAr[4];
#pragma unroll
  for (int reg = 0; reg < 4; ++reg) {
    float mT = -INFINITY, mS = -INFINITY, mA = -INFINITY;
#pragma unroll
    for (int t = 0; t < 8; ++t) {
      int c = cb + t * 16 + lr;
      float val = acc[t][reg] + bias_l[t];
      acc[t][reg] = val;
      if (c < 20) mT = fmaxf(mT, val);
      else if (c < 50) mS = fmaxf(mS, val);
      else if (c < 250) mA = fmaxf(mA, val);
    }
#pragma unroll
    for (int o = 8; o; o >>= 1) {
      mT = fmaxf(mT, __shfl_xor(mT, o, 64));
      mS = fmaxf(mS, __shfl_xor(mS, o, 64));
      mA = fmaxf(mA, __shfl_xor(mA, o, 64));
    }
    mTr[reg] = mT; mSr[reg] = mS; mAr[reg] = mA;
    if (lr == 0) aM[rg][ch][lg * 4 + reg] = mA;
  }
  __syncthreads();
#pragma unroll
  for (int reg = 0; reg < 4; ++reg)
    mAr[reg] = fmaxf(mAr[reg], aM[rg][ch ^ 1][lg * 4 + reg]);
  float sTr[4], sSr[4], sAr[4];
#pragma unroll
  for (int reg = 0; reg < 4; ++reg) {
    float sT = 0.f, sS = 0.f, sA = 0.f;
#pragma unroll
    for (int t = 0; t < 8; ++t) {
      int c = cb + t * 16 + lr;
      float m = (c < 20) ? mTr[reg] : (c < 50) ? mSr[reg] : mAr[reg];
      float e = __expf(acc[t][reg] - m);
      acc[t][reg] = e;
      if (c < 20) sT += e;
      else if (c < 50) sS += e;
      else if (c < 250) sA += e;
    }
#pragma unroll
    for (int o = 8; o; o >>= 1) {
      sT += __shfl_xor(sT, o, 64);
      sS += __shfl_xor(sS, o, 64);
      sA += __shfl_xor(sA, o, 64);
    }
    sTr[reg] = sT; sSr[reg] = sS; sAr[reg] = sA;
    if (lr == 0) aS[rg][ch][lg * 4 + reg] = sA;
  }
  __syncthreads();
#pragma unroll
  for (int reg = 0; reg < 4; ++reg)
    sAr[reg] += aS[rg][ch ^ 1][lg * 4 + reg];
  int rloc = r0 + lg * 4;
#pragma unroll
  for (int reg = 0; reg < 4; ++reg) {
    int row = rloc + reg;
    if (row >= n) continue;
    float iT = 1.f / sTr[reg], iS = 1.f / sSr[reg], iA = 1.f / sAr[reg];
#pragma unroll
    for (int t = 0; t < 8; ++t) {
      int c = cb + t * 16 + lr;
      float e = acc[t][reg];
      if (c < 20) outT[(size_t)row * 20 + c] = e * iT;
      else if (c < 50) outS[(size_t)row * 30 + (c - 20)] = e * iS;
      else if (c < 250) outA[(size_t)row * 200 + (c - 50)] = e * iA;
    }
  }
}

// ---------------------------------------------------------------------------
extern "C" void kernel_launch(void* const* d_in, const int* in_sizes, int n_in,
                              void* d_out, int out_size, void* d_ws, size_t ws_size,
                              hipStream_t stream) {
  const float* x0 = (const float*)d_in[0];
  const int* ei = (const int*)d_in[1];
  const float* W1 = (const float*)d_in[2];
  const float* b1 = (const float*)d_in[3];
  const float* Wt = (const float*)d_in[4];
  const float* bt = (const float*)d_in[5];
  const float* Ws = (const float*)d_in[6];
  const float* bs = (const float*)d_in[7];
  const float* Wa = (const float*)d_in[8];
  const float* ba = (const float*)d_in[9];
  const float* Wct = (const float*)d_in[10];
  const float* bct = (const float*)d_in[11];
  const float* Wcs = (const float*)d_in[12];
  const float* bcs = (const float*)d_in[13];
  const float* Wtf = (const float*)d_in[14];
  const float* btf = (const float*)d_in[15];
  const float* Wca = (const float*)d_in[16];
  const float* bca = (const float*)d_in[17];
  (void)n_in; (void)out_size; (void)ws_size;

  int N = in_sizes[0] / 128;
  int E = in_sizes[1] / 2;
  float* out = (float*)d_out;

  char* ws = (char*)d_ws;
  size_t off = 0;
  auto alloc = [&](size_t bytes) -> void* {
    void* p = ws + off;
    off = (off + bytes + 255) & ~(size_t)255;
    return p;
  };
  int* deg = (int*)alloc((size_t)N * 4);
  int* row_off = (int*)alloc((size_t)N * 4);
  int* bsum = (int*)alloc(256 * 4);
  int* cursor = (int*)alloc((size_t)N * 4);
  float* dinv = (float*)alloc((size_t)N * 4);
  unsigned short* csr = (unsigned short*)alloc((size_t)E * 2);
  unsigned short* WfPk = (unsigned short*)alloc((size_t)128 * 256 * 2);
  unsigned short* W1Pk = (unsigned short*)alloc((size_t)128 * 128 * 2);
  float* bfb = (float*)alloc(256 * 4);
  unsigned* Yb = (unsigned*)alloc((size_t)N * 64 * 4);
  unsigned* Ab = (unsigned*)alloc((size_t)N * 64 * 4);
  unsigned* Bb = (unsigned*)alloc((size_t)N * 64 * 4);

  GP gp;
  gp.x0 = x0;
  gp.src = ei;
  gp.dst = ei + E;
  gp.W1 = W1;
  gp.Wt = Wt; gp.bt = bt; gp.Wct = Wct; gp.bct = bct;
  gp.Ws = Ws; gp.bs = bs; gp.Wcs = Wcs; gp.bcs = bcs;
  gp.Wa = Wa; gp.ba = ba; gp.Wca = Wca; gp.bca = bca;
  gp.deg = deg; gp.row_off = row_off; gp.bsum = bsum; gp.cursor = cursor;
  gp.dinv = dinv; gp.csr = csr; gp.WfPk = WfPk; gp.W1Pk = W1Pk; gp.bfb = bfb;
  gp.Yb = Yb;
  gp.N = N; gp.E = E; gp.gN = (N + 255) / 256;

  // cooperative setup launch: grid sized from occupancy (guaranteed resident)
  int occ = 0;
  hipOccupancyMaxActiveBlocksPerMultiprocessor(&occ, k_setup_coop, 256, 0);
  if (occ < 1) occ = 1;
  if (occ > 4) occ = 4;
  int sgrid = 256 * occ;  // 256 CUs on MI355X
  void* kargs[] = {(void*)&gp};
  hipLaunchCooperativeKernel((void*)k_setup_coop, dim3(sgrid), dim3(256), kargs,
                             0, stream);

  int g32 = (N + 31) / 32;
  int gT = (N + 15) / 16;
  // Ab = agg(Yb)
  k_agg<<<(N + 7) / 8, 256, 0, stream>>>(Yb, Ab, row_off, deg, csr, dinv, N);
  // Bb = bf16(dinv*relu(Ab@W1+b1))
  k_mfma_gemm128<<<g32, 256, 0, stream>>>(
      (const short*)Ab, W1Pk, b1, dinv, (unsigned short*)Bb, N);
  // Ab = agg(Bb)
  k_agg<<<(N + 7) / 8, 256, 0, stream>>>(Bb, Ab, row_off, deg, csr, dinv, N);
  // heads + time in one grid
  k_heads_time<<<g32 + gT, 256, 0, stream>>>(
      (const short*)Ab, WfPk, bfb, x0, Wtf, btf,
      out, out + (size_t)N * 20, out + (size_t)N * 50, out + (size_t)N * 65, N);
}

// Round 11
// 337.081 us; speedup vs baseline: 1.5701x; 1.5701x over previous
//
#include <hip/hip_runtime.h>
#include <math.h>

// ---------------------------------------------------------------------------
// GCN forward. R10: revert cooperative setup (R9 regression). Fuse the sparse
// aggregation INTO the MFMA consumers: each block aggregates its 32 rows
// straight into LDS (bf16), then runs the GEMM/heads on them. Kills the Ab
// global round-trip and 2 launches. 9 dispatches total.
// ---------------------------------------------------------------------------

typedef short short8 __attribute__((ext_vector_type(8)));
typedef float f32x4 __attribute__((ext_vector_type(4)));

static __device__ __forceinline__ unsigned short f2bf(float x) {  // RNE
  unsigned u = __float_as_uint(x);
  u += 0x7fff + ((u >> 16) & 1);
  return (unsigned short)(u >> 16);
}
static __device__ __forceinline__ unsigned pack2bf(float lo, float hi) {
  return ((unsigned)f2bf(hi) << 16) | (unsigned)f2bf(lo);
}
static __device__ __forceinline__ float bflo(unsigned u) {
  return __uint_as_float(u << 16);
}
static __device__ __forceinline__ float bfhi(unsigned u) {
  return __uint_as_float(u & 0xffff0000u);
}

// ---- degree count ---------------------------------------------------------
__global__ void k_deg(const int* __restrict__ dst, int E, int* __restrict__ deg) {
  int e = blockIdx.x * blockDim.x + threadIdx.x;
  if (e < E) atomicAdd(&deg[dst[e]], 1);
}

// ---- scan: per-chunk then chunk-sums --------------------------------------
__global__ void k_scan1(const int* __restrict__ deg, int n,
                        int* __restrict__ excl, int* __restrict__ bsum) {
  __shared__ int sm[256];
  int i = blockIdx.x * 256 + threadIdx.x;
  int v = (i < n) ? deg[i] : 0;
  sm[threadIdx.x] = v;
  __syncthreads();
#pragma unroll
  for (int o = 1; o < 256; o <<= 1) {
    int t = (threadIdx.x >= o) ? sm[threadIdx.x - o] : 0;
    __syncthreads();
    sm[threadIdx.x] += t;
    __syncthreads();
  }
  if (i < n) excl[i] = sm[threadIdx.x] - v;
  if (threadIdx.x == 255) bsum[blockIdx.x] = sm[255];
}

__global__ void k_scan2(int* __restrict__ bsum, int nb) {
  __shared__ int sm[256];
  int v = (threadIdx.x < nb) ? bsum[threadIdx.x] : 0;
  sm[threadIdx.x] = v;
  __syncthreads();
#pragma unroll
  for (int o = 1; o < 256; o <<= 1) {
    int t = (threadIdx.x >= o) ? sm[threadIdx.x - o] : 0;
    __syncthreads();
    sm[threadIdx.x] += t;
    __syncthreads();
  }
  if (threadIdx.x < nb) bsum[threadIdx.x] = sm[threadIdx.x] - v;  // exclusive
}

// ---- fused finalize (row_off/cursor/dinv) + pre-scale x0 -> bf16 ----------
__global__ __launch_bounds__(256) void k_finscale(
    const float* __restrict__ X, const int* __restrict__ deg,
    const int* __restrict__ bsum, int* __restrict__ row_off,
    int* __restrict__ cursor, float* __restrict__ dinv,
    unsigned* __restrict__ Y, int n) {
  int p = blockIdx.x * 256 + threadIdx.x;  // pair index (2 cols)
  if (p >= n * 64) return;
  int row = p >> 6;
  float d = rsqrtf((float)(deg[row] + 1));  // +1 self-loop
  if ((p & 63) == 0) {
    int ro = row_off[row] + bsum[row >> 8];
    row_off[row] = ro;
    cursor[row] = ro;
    dinv[row] = d;
  }
  float2 v = reinterpret_cast<const float2*>(X)[p];
  Y[p] = pack2bf(v.x * d, v.y * d);
}

// ---- CSR fill (uint16) ----------------------------------------------------
__global__ void k_fill(const int* __restrict__ src, const int* __restrict__ dst,
                       int E, int* __restrict__ cursor,
                       unsigned short* __restrict__ csr) {
  int e = blockIdx.x * blockDim.x + threadIdx.x;
  if (e < E) {
    int d = dst[e];
    int p = atomicAdd(&cursor[d], 1);
    csr[p] = (unsigned short)src[e];
  }
}

// ---- fused: head-weight fusion (blocks 0..255) + W1 packing (256..383) ----
__global__ void k_fusepack(
    const float* __restrict__ Wt, const float* __restrict__ bt,
    const float* __restrict__ Wct, const float* __restrict__ bct,
    const float* __restrict__ Ws, const float* __restrict__ bs,
    const float* __restrict__ Wcs, const float* __restrict__ bcs,
    const float* __restrict__ Wa, const float* __restrict__ ba,
    const float* __restrict__ Wca, const float* __restrict__ bca,
    unsigned short* __restrict__ WfPk, float* __restrict__ bf,
    const float* __restrict__ W1, unsigned short* __restrict__ W1Pk) {
  if (blockIdx.x >= 256) {  // pack W1 [128][128] -> [(k>>3)][col][k&7]
    int t = (blockIdx.x - 256) * 128 + threadIdx.x;
    int i = t >> 7, c = t & 127;
    W1Pk[((i >> 3) * 128 + c) * 8 + (i & 7)] = f2bf(W1[t]);
    return;
  }
  int c = blockIdx.x;
  int i = threadIdx.x;  // 0..127
  float acc = 0.f, bacc = 0.f;
  if (c < 20) {
    for (int k = 0; k < 20; ++k) {
      float w2 = Wct[k * 20 + c];
      acc += Wt[i * 20 + k] * w2;
      bacc += bt[k] * w2;
    }
    bacc += bct[c];
  } else if (c < 50) {
    int cc = c - 20;
    for (int k = 0; k < 30; ++k) {
      float w2 = Wcs[k * 30 + cc];
      acc += Ws[i * 30 + k] * w2;
      bacc += bs[k] * w2;
    }
    bacc += bcs[cc];
  } else if (c < 250) {
    int cc = c - 50;
    for (int k = 0; k < 200; ++k) {
      float w2 = Wca[k * 200 + cc];
      acc += Wa[i * 200 + k] * w2;
      bacc += ba[k] * w2;
    }
    bacc += bca[cc];
  }
  WfPk[((i >> 3) * 256 + c) * 8 + (i & 7)] = f2bf(acc);
  if (i == 0) bf[c] = bacc;
}

// ---- aggregate 32 rows directly into LDS (bf16) ---------------------------
// wave w handles 8 nodes (2 at a time); lane: sub=node, sl=uint2 col chunk.
static __device__ __forceinline__ void agg_to_lds(
    const unsigned* __restrict__ Y, short (*sAb)[136], int rowBase,
    const int* __restrict__ row_off, const int* __restrict__ deg,
    const unsigned short* __restrict__ csr, const float* __restrict__ dinv,
    int n, int tid) {
  int wave = tid >> 6, lane = tid & 63;
  int sub = lane >> 5, sl = lane & 31;
  const uint2* Yv = reinterpret_cast<const uint2*>(Y);
#pragma unroll
  for (int it = 0; it < 4; ++it) {
    int r = wave * 8 + it * 2 + sub;  // 0..31
    int i = rowBase + r;
    uint2 rr;
    if (i < n) {
      int start = row_off[i];
      int cnt = deg[i];
      float a0 = 0.f, a1 = 0.f, a2 = 0.f, a3 = 0.f;
      int j = 0;
      for (; j + 3 < cnt; j += 4) {
        int s0 = csr[start + j];
        int s1 = csr[start + j + 1];
        int s2 = csr[start + j + 2];
        int s3 = csr[start + j + 3];
        uint2 u0 = Yv[(size_t)s0 * 32 + sl];
        uint2 u1 = Yv[(size_t)s1 * 32 + sl];
        uint2 u2 = Yv[(size_t)s2 * 32 + sl];
        uint2 u3 = Yv[(size_t)s3 * 32 + sl];
        a0 += (bflo(u0.x) + bflo(u1.x)) + (bflo(u2.x) + bflo(u3.x));
        a1 += (bfhi(u0.x) + bfhi(u1.x)) + (bfhi(u2.x) + bfhi(u3.x));
        a2 += (bflo(u0.y) + bflo(u1.y)) + (bflo(u2.y) + bflo(u3.y));
        a3 += (bfhi(u0.y) + bfhi(u1.y)) + (bfhi(u2.y) + bfhi(u3.y));
      }
      for (; j < cnt; ++j) {
        int s0 = csr[start + j];
        uint2 u0 = Yv[(size_t)s0 * 32 + sl];
        a0 += bflo(u0.x);
        a1 += bfhi(u0.x);
        a2 += bflo(u0.y);
        a3 += bfhi(u0.y);
      }
      uint2 us = Yv[(size_t)i * 32 + sl];
      float di = dinv[i];
      rr.x = pack2bf((a0 + bflo(us.x)) * di, (a1 + bfhi(us.x)) * di);
      rr.y = pack2bf((a2 + bflo(us.y)) * di, (a3 + bfhi(us.y)) * di);
    } else {
      rr.x = 0u;
      rr.y = 0u;
    }
    *reinterpret_cast<uint2*>(&sAb[r][sl * 4]) = rr;
  }
}

// ---- fused agg + MFMA GEMM 128x128 (col-split) ----------------------------
// out = bf16(dinv[r]*relu(agg(Y)[r] @ W1 + b))
__global__ __launch_bounds__(256) void k_agg_gemm128(
    const unsigned* __restrict__ Y, const int* __restrict__ row_off,
    const int* __restrict__ deg, const unsigned short* __restrict__ csr,
    const float* __restrict__ dinv, const unsigned short* __restrict__ Wpk,
    const float* __restrict__ bias, unsigned short* __restrict__ out, int n) {
  __shared__ short sAb[32][136];
  int rowBase = blockIdx.x * 32;
  agg_to_lds(Y, sAb, rowBase, row_off, deg, csr, dinv, n, threadIdx.x);
  __syncthreads();
  int wave = threadIdx.x >> 6, lane = threadIdx.x & 63;
  int rg = wave >> 1, ch = wave & 1;
  int lr = lane & 15, lg = lane >> 4;
  int r0 = rowBase + rg * 16;
  short8 afr[4];
#pragma unroll
  for (int kk = 0; kk < 4; ++kk)
    afr[kk] = *reinterpret_cast<const short8*>(&sAb[rg * 16 + lr][kk * 32 + lg * 8]);
  f32x4 acc[4];
#pragma unroll
  for (int t = 0; t < 4; ++t) acc[t] = (f32x4){0.f, 0.f, 0.f, 0.f};
  const short8* Wp8 = reinterpret_cast<const short8*>(Wpk);
#pragma unroll
  for (int t = 0; t < 4; ++t) {
#pragma unroll
    for (int kk = 0; kk < 4; ++kk) {
      short8 bfr = Wp8[(kk * 4 + lg) * 128 + ch * 64 + t * 16 + lr];
      acc[t] = __builtin_amdgcn_mfma_f32_16x16x32_bf16(afr[kk], bfr, acc[t], 0, 0, 0);
    }
  }
  int rloc = r0 + lg * 4;
#pragma unroll
  for (int t = 0; t < 4; ++t) {
    int col = ch * 64 + t * 16 + lr;
    float b = bias[col];
#pragma unroll
    for (int reg = 0; reg < 4; ++reg) {
      int row = rloc + reg;
      if (row < n) {
        float v = fmaxf(acc[t][reg] + b, 0.f) * dinv[row];
        out[(size_t)row * 128 + col] = f2bf(v);
      }
    }
  }
}

// ---- fused agg + heads MFMA (col-split) + segmented softmax + time head ---
__global__ __launch_bounds__(256) void k_agg_heads_time(
    const unsigned* __restrict__ Y, const int* __restrict__ row_off,
    const int* __restrict__ deg, const unsigned short* __restrict__ csr,
    const float* __restrict__ dinv, const unsigned short* __restrict__ Wpk,
    const float* __restrict__ bfb, const float* __restrict__ x0,
    const float* __restrict__ Wtf, const float* __restrict__ btf,
    float* __restrict__ outT, float* __restrict__ outS,
    float* __restrict__ outTime, float* __restrict__ outA, int n) {
  int g32 = (n + 31) / 32;
  if ((int)blockIdx.x >= g32) {
    // ---------------- time head: softmax(x0 @ Wtf + btf), no LDS ----------
    int tb = blockIdx.x - g32;
    int j = threadIdx.x & 15;
    int rl = threadIdx.x >> 4;
    int r = tb * 16 + rl;
    if (r >= n) return;
    int jj = (j < 15) ? j : 14;
    float acc = btf[jj];
    const float4* xr = reinterpret_cast<const float4*>(x0 + (size_t)r * 128);
    for (int k4 = 0; k4 < 32; ++k4) {
      float4 xv = xr[k4];
      acc += xv.x * Wtf[(k4 * 4 + 0) * 15 + jj] + xv.y * Wtf[(k4 * 4 + 1) * 15 + jj] +
             xv.z * Wtf[(k4 * 4 + 2) * 15 + jj] + xv.w * Wtf[(k4 * 4 + 3) * 15 + jj];
    }
    float m = (j < 15) ? acc : -INFINITY;
#pragma unroll
    for (int o = 8; o; o >>= 1) m = fmaxf(m, __shfl_xor(m, o, 16));
    float e = (j < 15) ? __expf(acc - m) : 0.f;
    float s = e;
#pragma unroll
    for (int o = 8; o; o >>= 1) s += __shfl_xor(s, o, 16);
    if (j < 15) outTime[(size_t)r * 15 + j] = e / s;
    return;
  }
  // ---------------- heads (agg -> LDS -> MFMA -> softmax) ----------------
  __shared__ short sAb[32][136];
  __shared__ float aM[2][2][16];
  __shared__ float aS[2][2][16];
  int rowBase = blockIdx.x * 32;
  agg_to_lds(Y, sAb, rowBase, row_off, deg, csr, dinv, n, threadIdx.x);
  __syncthreads();
  int wave = threadIdx.x >> 6, lane = threadIdx.x & 63;
  int rg = wave >> 1, ch = wave & 1;
  int lr = lane & 15, lg = lane >> 4;
  int r0 = rowBase + rg * 16;
  int cb = ch * 128;
  short8 afr[4];
#pragma unroll
  for (int kk = 0; kk < 4; ++kk)
    afr[kk] = *reinterpret_cast<const short8*>(&sAb[rg * 16 + lr][kk * 32 + lg * 8]);
  f32x4 acc[8];
#pragma unroll
  for (int t = 0; t < 8; ++t) acc[t] = (f32x4){0.f, 0.f, 0.f, 0.f};
  const short8* Wp8 = reinterpret_cast<const short8*>(Wpk);
#pragma unroll
  for (int t = 0; t < 8; ++t) {
#pragma unroll
    for (int kk = 0; kk < 4; ++kk) {
      short8 bfr = Wp8[(kk * 4 + lg) * 256 + cb + t * 16 + lr];
      acc[t] = __builtin_amdgcn_mfma_f32_16x16x32_bf16(afr[kk], bfr, acc[t], 0, 0, 0);
    }
  }
  float bias_l[8];
#pragma unroll
  for (int t = 0; t < 8; ++t) bias_l[t] = bfb[cb + t * 16 + lr];
  float mTr[4], mSr[4], mAr[4];
#pragma unroll
  for (int reg = 0; reg < 4; ++reg) {
    float mT = -INFINITY, mS = -INFINITY, mA = -INFINITY;
#pragma unroll
    for (int t = 0; t < 8; ++t) {
      int c = cb + t * 16 + lr;
      float val = acc[t][reg] + bias_l[t];
      acc[t][reg] = val;
      if (c < 20) mT = fmaxf(mT, val);
      else if (c < 50) mS = fmaxf(mS, val);
      else if (c < 250) mA = fmaxf(mA, val);
    }
#pragma unroll
    for (int o = 8; o; o >>= 1) {
      mT = fmaxf(mT, __shfl_xor(mT, o, 64));
      mS = fmaxf(mS, __shfl_xor(mS, o, 64));
      mA = fmaxf(mA, __shfl_xor(mA, o, 64));
    }
    mTr[reg] = mT; mSr[reg] = mS; mAr[reg] = mA;
    if (lr == 0) aM[rg][ch][lg * 4 + reg] = mA;
  }
  __syncthreads();
#pragma unroll
  for (int reg = 0; reg < 4; ++reg)
    mAr[reg] = fmaxf(mAr[reg], aM[rg][ch ^ 1][lg * 4 + reg]);
  float sTr[4], sSr[4], sAr[4];
#pragma unroll
  for (int reg = 0; reg < 4; ++reg) {
    float sT = 0.f, sS = 0.f, sA = 0.f;
#pragma unroll
    for (int t = 0; t < 8; ++t) {
      int c = cb + t * 16 + lr;
      float m = (c < 20) ? mTr[reg] : (c < 50) ? mSr[reg] : mAr[reg];
      float e = __expf(acc[t][reg] - m);
      acc[t][reg] = e;
      if (c < 20) sT += e;
      else if (c < 50) sS += e;
      else if (c < 250) sA += e;
    }
#pragma unroll
    for (int o = 8; o; o >>= 1) {
      sT += __shfl_xor(sT, o, 64);
      sS += __shfl_xor(sS, o, 64);
      sA += __shfl_xor(sA, o, 64);
    }
    sTr[reg] = sT; sSr[reg] = sS; sAr[reg] = sA;
    if (lr == 0) aS[rg][ch][lg * 4 + reg] = sA;
  }
  __syncthreads();
#pragma unroll
  for (int reg = 0; reg < 4; ++reg)
    sAr[reg] += aS[rg][ch ^ 1][lg * 4 + reg];
  int rloc = r0 + lg * 4;
#pragma unroll
  for (int reg = 0; reg < 4; ++reg) {
    int row = rloc + reg;
    if (row >= n) continue;
    float iT = 1.f / sTr[reg], iS = 1.f / sSr[reg], iA = 1.f / sAr[reg];
#pragma unroll
    for (int t = 0; t < 8; ++t) {
      int c = cb + t * 16 + lr;
      float e = acc[t][reg];
      if (c < 20) outT[(size_t)row * 20 + c] = e * iT;
      else if (c < 50) outS[(size_t)row * 30 + (c - 20)] = e * iS;
      else if (c < 250) outA[(size_t)row * 200 + (c - 50)] = e * iA;
    }
  }
}

// ---------------------------------------------------------------------------
extern "C" void kernel_launch(void* const* d_in, const int* in_sizes, int n_in,
                              void* d_out, int out_size, void* d_ws, size_t ws_size,
                              hipStream_t stream) {
  const float* x0 = (const float*)d_in[0];
  const int* ei = (const int*)d_in[1];
  const float* W1 = (const float*)d_in[2];
  const float* b1 = (const float*)d_in[3];
  const float* Wt = (const float*)d_in[4];
  const float* bt = (const float*)d_in[5];
  const float* Ws = (const float*)d_in[6];
  const float* bs = (const float*)d_in[7];
  const float* Wa = (const float*)d_in[8];
  const float* ba = (const float*)d_in[9];
  const float* Wct = (const float*)d_in[10];
  const float* bct = (const float*)d_in[11];
  const float* Wcs = (const float*)d_in[12];
  const float* bcs = (const float*)d_in[13];
  const float* Wtf = (const float*)d_in[14];
  const float* btf = (const float*)d_in[15];
  const float* Wca = (const float*)d_in[16];
  const float* bca = (const float*)d_in[17];
  (void)n_in; (void)out_size; (void)ws_size;

  int N = in_sizes[0] / 128;
  int E = in_sizes[1] / 2;
  float* out = (float*)d_out;

  char* ws = (char*)d_ws;
  size_t off = 0;
  auto alloc = [&](size_t bytes) -> void* {
    void* p = ws + off;
    off = (off + bytes + 255) & ~(size_t)255;
    return p;
  };
  int* deg = (int*)alloc((size_t)N * 4);
  int* row_off = (int*)alloc((size_t)N * 4);
  int* bsum = (int*)alloc(256 * 4);
  int* cursor = (int*)alloc((size_t)N * 4);
  float* dinv = (float*)alloc((size_t)N * 4);
  unsigned short* csr = (unsigned short*)alloc((size_t)E * 2);
  unsigned short* WfPk = (unsigned short*)alloc((size_t)128 * 256 * 2);
  unsigned short* W1Pk = (unsigned short*)alloc((size_t)128 * 128 * 2);
  float* bfb = (float*)alloc(256 * 4);
  unsigned* Yb = (unsigned*)alloc((size_t)N * 64 * 4);  // bf16 (pre-scaled x0)
  unsigned* Bb = (unsigned*)alloc((size_t)N * 64 * 4);  // bf16 (hidden)

  const int* srcp = ei;
  const int* dstp = ei + E;
  int gE = (E + 255) / 256;
  int gN = (N + 255) / 256;  // 196 <= 256, required by k_scan2
  int g32 = (N + 31) / 32;
  int gT = (N + 15) / 16;

  hipMemsetAsync(deg, 0, (size_t)N * 4, stream);
  k_deg<<<gE, 256, 0, stream>>>(dstp, E, deg);
  k_scan1<<<gN, 256, 0, stream>>>(deg, N, row_off, bsum);
  k_scan2<<<1, 256, 0, stream>>>(bsum, gN);
  k_finscale<<<(N * 64 + 255) / 256, 256, 0, stream>>>(
      x0, deg, bsum, row_off, cursor, dinv, Yb, N);
  k_fill<<<gE, 256, 0, stream>>>(srcp, dstp, E, cursor, csr);
  k_fusepack<<<384, 128, 0, stream>>>(Wt, bt, Wct, bct, Ws, bs, Wcs, bcs, Wa, ba,
                                      Wca, bca, WfPk, bfb, W1, W1Pk);
  // Bb = bf16(dinv*relu(agg(Yb)@W1+b1))   [fused agg+MFMA]
  k_agg_gemm128<<<g32, 256, 0, stream>>>(Yb, row_off, deg, csr, dinv, W1Pk, b1,
                                         (unsigned short*)Bb, N);
  // heads + time: agg(Bb) -> MFMA -> segmented softmax  [fused]
  k_agg_heads_time<<<g32 + gT, 256, 0, stream>>>(
      Bb, row_off, deg, csr, dinv, WfPk, bfb, x0, Wtf, btf,
      out, out + (size_t)N * 20, out + (size_t)N * 50, out + (size_t)N * 65, N);
}